// Round 5
// baseline (885.868 us; speedup 1.0000x reference)
//
#include <hip/hip_runtime.h>

#define NN 40000
#define EE 400000

typedef short short8 __attribute__((ext_vector_type(8)));
typedef float f32x4 __attribute__((ext_vector_type(4)));
typedef unsigned short ushort4_ __attribute__((ext_vector_type(4)));

__device__ __forceinline__ unsigned short f2bf(float f) {
  unsigned int u = __float_as_uint(f);
  u = (u + 0x7FFFu + ((u >> 16) & 1u)) >> 16;
  return (unsigned short)u;
}

__device__ __forceinline__ f32x4 ld_bf4(const unsigned short* p) {
  ushort4_ u = *(const ushort4_*)p;
  f32x4 r;
  r[0] = __uint_as_float((unsigned int)u[0] << 16);
  r[1] = __uint_as_float((unsigned int)u[1] << 16);
  r[2] = __uint_as_float((unsigned int)u[2] << 16);
  r[3] = __uint_as_float((unsigned int)u[3] << 16);
  return r;
}

// ---- f32 -> bf16 for the 6 node-feature matrices --------------------------
__global__ __launch_bounds__(256) void k_convx(
    const float* __restrict__ x0, const float* __restrict__ x1, const float* __restrict__ x2,
    const float* __restrict__ x3, const float* __restrict__ x4, const float* __restrict__ x5,
    unsigned short* __restrict__ xb) {
  int z = blockIdx.y;
  const float* x;
  switch (z) { case 0: x = x0; break; case 1: x = x1; break; case 2: x = x2; break;
               case 3: x = x3; break; case 4: x = x4; break; default: x = x5; break; }
  size_t i = ((size_t)blockIdx.x * 256 + threadIdx.x) * 4;
  f32x4 v = *(const f32x4*)(x + i);
  ushort4_ o;
  o[0] = f2bf(v[0]); o[1] = f2bf(v[1]); o[2] = f2bf(v[2]); o[3] = f2bf(v[3]);
  *(ushort4_*)(xb + (size_t)z * (NN * 256) + i) = o;
}

// ---- W -> bf16, k-tiled transposed: wt2[r][kt][n][k0] = W[r][kt*32+k0][n] --
__global__ __launch_bounds__(256) void k_wt2(const float* __restrict__ W,
                                             unsigned short* __restrict__ wt2) {
  int idx = blockIdx.x * 256 + threadIdx.x;  // < 262144
  int k0 = idx & 31, n = (idx >> 5) & 255, kt = (idx >> 13) & 7, r = idx >> 16;
  float v = W[((size_t)(r * 256) + (kt * 32 + k0)) * 256 + n];
  wt2[idx] = f2bf(v);
}

// ---- weff[q][f][j] = sum_c W[r][f][j*32+c] * att[r][j][c], q = r*2+side ----
__global__ __launch_bounds__(256) void k_weff(const float* __restrict__ W,
                                              const float* __restrict__ asrc,
                                              const float* __restrict__ adst,
                                              float* __restrict__ weff) {
  int idx = blockIdx.x * 256 + threadIdx.x;  // < 16384
  int j = idx & 7, f = (idx >> 3) & 255, q = idx >> 11;
  int r = q >> 1, side = q & 1;
  const float* att = side ? adst : asrc;
  const float* wrow = W + ((size_t)(r * 256) + f) * 256 + j * 32;
  const float* arow = att + (r * 8 + j) * 32;
  float s = 0.f;
#pragma unroll
  for (int c = 0; c < 32; ++c) s += wrow[c] * arow[c];
  weff[idx] = s;
}

// ---- weff -> bf16 k-tiled B layout: weffb[kt][col][k0], col = q*8 + j ------
__global__ __launch_bounds__(256) void k_weffb(const float* __restrict__ weff,
                                               unsigned short* __restrict__ weffb) {
  int idx = blockIdx.x * 256 + threadIdx.x;  // < 16384
  int k0 = idx & 31, col = (idx >> 5) & 63, kt = idx >> 11;
  int q = col >> 3, j = col & 7;
  int f = kt * 32 + k0;
  weffb[idx] = f2bf(weff[(q * 256 + f) * 8 + j]);
}

// ---- CSR build ------------------------------------------------------------
__global__ __launch_bounds__(256) void k_zero(int* __restrict__ p, int n) {
  int i = blockIdx.x * 256 + threadIdx.x;
  if (i < n) p[i] = 0;
}

__global__ __launch_bounds__(256) void k_hist(
    const int* __restrict__ e0, const int* __restrict__ e1,
    const int* __restrict__ e2, const int* __restrict__ e3, int* __restrict__ cnt) {
  int r = blockIdx.y;
  const int* ei = (r == 0) ? e0 : (r == 1) ? e1 : (r == 2) ? e2 : e3;
  int e = blockIdx.x * 256 + threadIdx.x;
  if (e < EE) atomicAdd(&cnt[r * NN + ei[EE + e]], 1);
}

__global__ __launch_bounds__(1024) void k_scan(const int* __restrict__ cnt,
                                               int* __restrict__ rowptr,
                                               int* __restrict__ cursor) {
  int r = blockIdx.x;
  const int* c = cnt + r * NN;
  int* rp = rowptr + r * (NN + 1);
  int* cur = cursor + r * NN;
  __shared__ int part[1024];
  int t = threadIdx.x;
  const int per = 40;  // 1024*40 >= 40000
  int base = t * per;
  int sum = 0;
  for (int i = 0; i < per; ++i) { int idx = base + i; if (idx < NN) sum += c[idx]; }
  part[t] = sum;
  __syncthreads();
  for (int o = 1; o < 1024; o <<= 1) {
    int v = (t >= o) ? part[t - o] : 0;
    __syncthreads();
    part[t] += v;
    __syncthreads();
  }
  int run = part[t] - sum;  // exclusive prefix
  for (int i = 0; i < per; ++i) {
    int idx = base + i;
    if (idx < NN) { rp[idx] = run; cur[idx] = run; run += c[idx]; }
  }
  if (t == 1023) rp[NN] = part[1023];
}

__global__ __launch_bounds__(256) void k_scatter(
    const int* __restrict__ e0, const int* __restrict__ e1,
    const int* __restrict__ e2, const int* __restrict__ e3,
    int* __restrict__ cursor, int* __restrict__ adj) {
  int r = blockIdx.y;
  const int* ei = (r == 0) ? e0 : (r == 1) ? e1 : (r == 2) ? e2 : e3;
  int e = blockIdx.x * 256 + threadIdx.x;
  if (e < EE) {
    int s = ei[e], d = ei[EE + e];
    int pos = atomicAdd(&cursor[r * NN + d], 1);
    adj[(size_t)r * EE + pos] = s;
  }
}

// ---- attention logits via MFMA: alx[z][q][n][8] = (xb[z] @ weffb) ----------
__global__ __launch_bounds__(256) void k_algemm(const unsigned short* __restrict__ xb,
                                                const unsigned short* __restrict__ weffb,
                                                float* __restrict__ alx) {
  __shared__ __attribute__((aligned(16))) unsigned short Alds[64][40];
  __shared__ __attribute__((aligned(16))) unsigned short Blds[64][40];
  int z = blockIdx.y;
  const unsigned short* xbp = xb + (size_t)z * (NN * 256);
  int tid = threadIdx.x;
  int wave = tid >> 6, lane = tid & 63;
  int l15 = lane & 15, l16 = lane >> 4;
  int row0 = blockIdx.x * 64;
  f32x4 acc[4] = {};
  int ar = tid >> 2, ac = (tid & 3) * 8;
  const unsigned short* aglob = xbp + (size_t)(row0 + ar) * 256 + ac;
  for (int kt = 0; kt < 8; ++kt) {
    short8 av = *(const short8*)(aglob + kt * 32);
    *(short8*)(&Alds[ar][ac]) = av;
    short8 bv = *(const short8*)(weffb + kt * 2048 + tid * 8);
    *(short8*)(&Blds[tid >> 2][(tid & 3) * 8]) = bv;
    __syncthreads();
    short8 bf = *(const short8*)(&Blds[wave * 16 + l15][l16 * 8]);
#pragma unroll
    for (int mt = 0; mt < 4; ++mt) {
      short8 af = *(const short8*)(&Alds[mt * 16 + l15][l16 * 8]);
      acc[mt] = __builtin_amdgcn_mfma_f32_16x16x32_bf16(af, bf, acc[mt], 0, 0, 0);
    }
    __syncthreads();
  }
  int col = wave * 16 + l15;
  int q = col >> 3, jj = col & 7;
#pragma unroll
  for (int mt = 0; mt < 4; ++mt)
#pragma unroll
    for (int rr = 0; rr < 4; ++rr) {
      int row = row0 + mt * 16 + l16 * 4 + rr;
      alx[(((size_t)z * 8 + q) * NN + row) * 8 + jj] = acc[mt][rr];
    }
}

// ---- per-head global max of alsrc column, stage 1: 32 slices of 1250 ------
// grid (8 = g*4+r, 32 = slice); pmax[(gr*32+slice)*8 + h]
__global__ __launch_bounds__(256) void k_maxsrcp(const float* __restrict__ alx,
                                                 float* __restrict__ pmax) {
  const int srct[4] = {0, 1, 0, 2};
  int gr = blockIdx.x, slice = blockIdx.y;
  int g = gr >> 2, r = gr & 3;
  const float* col = alx + ((size_t)((g * 3 + srct[r]) * 8 + 2 * r) * NN) * 8;
  int t = threadIdx.x;
  int h = t & 7, chunk = t >> 3;  // 32 chunks
  float m = -1e30f;
  for (int nn = chunk; nn < 1250; nn += 32)
    m = fmaxf(m, col[(size_t)(slice * 1250 + nn) * 8 + h]);
  __shared__ float red[256];
  red[t] = m;
  __syncthreads();
  for (int o = 128; o >= 8; o >>= 1) {
    if (t < o) red[t] = fmaxf(red[t], red[t + o]);
    __syncthreads();
  }
  if (t < 8) pmax[(gr * 32 + slice) * 8 + t] = red[t];
}

// ---- stage 2: reduce 32 slices -> maxsrc[gr*8+h] --------------------------
__global__ __launch_bounds__(64) void k_maxfin(const float* __restrict__ pmax,
                                               float* __restrict__ maxsrc) {
  int t = threadIdx.x;  // 64 = 8 gr * 8 h
  int gr = t >> 3, h = t & 7;
  float m = -1e30f;
  for (int s = 0; s < 32; ++s) m = fmaxf(m, pmax[(gr * 32 + s) * 8 + h]);
  maxsrc[t] = m;
}

// ---- bf16 MFMA GEMM (batched over r): hb[r][40000][256] = bf16(xb @ W) ----
__global__ __launch_bounds__(256) void k_gemmb4(const unsigned short* __restrict__ xb,
                                                const unsigned short* __restrict__ wt2,
                                                unsigned short* __restrict__ hb4, int g) {
  __shared__ __attribute__((aligned(16))) unsigned short Alds[64][40];
  __shared__ __attribute__((aligned(16))) unsigned short Blds[256][40];
  const int srct[4] = {0, 1, 0, 2};
  int r = blockIdx.y;
  const unsigned short* xbp = xb + (size_t)(g * 3 + srct[r]) * (NN * 256);
  const unsigned short* wtp = wt2 + (size_t)r * (8 * 256 * 32);
  unsigned short* hbp = hb4 + (size_t)r * (NN * 256);
  int tid = threadIdx.x;
  int wave = tid >> 6, lane = tid & 63;
  int l15 = lane & 15, l16 = lane >> 4;
  int row0 = blockIdx.x * 64;
  f32x4 acc[4][4] = {};
  int ar = tid >> 2, ac = (tid & 3) * 8;
  const unsigned short* aglob = xbp + (size_t)(row0 + ar) * 256 + ac;
  for (int kt = 0; kt < 8; ++kt) {
    short8 av = *(const short8*)(aglob + kt * 32);
    *(short8*)(&Alds[ar][ac]) = av;
    const unsigned short* bsrc = wtp + kt * (256 * 32);
#pragma unroll
    for (int i = 0; i < 4; ++i) {
      int cidx = tid + 256 * i;
      short8 bv = *(const short8*)(bsrc + cidx * 8);
      *(short8*)(&Blds[cidx >> 2][(cidx & 3) * 8]) = bv;
    }
    __syncthreads();
    short8 af[4], bf[4];
#pragma unroll
    for (int mt = 0; mt < 4; ++mt) af[mt] = *(const short8*)(&Alds[mt * 16 + l15][l16 * 8]);
#pragma unroll
    for (int nt = 0; nt < 4; ++nt) bf[nt] = *(const short8*)(&Blds[wave * 64 + nt * 16 + l15][l16 * 8]);
#pragma unroll
    for (int mt = 0; mt < 4; ++mt)
#pragma unroll
      for (int nt = 0; nt < 4; ++nt)
        acc[mt][nt] = __builtin_amdgcn_mfma_f32_16x16x32_bf16(af[mt], bf[nt], acc[mt][nt], 0, 0, 0);
    __syncthreads();
  }
#pragma unroll
  for (int mt = 0; mt < 4; ++mt)
#pragma unroll
    for (int nt = 0; nt < 4; ++nt)
#pragma unroll
      for (int rr = 0; rr < 4; ++rr)
        hbp[(size_t)(row0 + mt * 16 + l16 * 4 + rr) * 256 + wave * 64 + nt * 16 + l15] =
            f2bf(acc[mt][nt][rr]);
}

// ---- one-relation softmax aggregation, upper-bound shift (no max chain) ---
// lane layout: head h = lane>>3, edge slot e8 = lane&7
__device__ __forceinline__ f32x4 agg_one(
    int r, int g, int d, int lane,
    const int* __restrict__ rowptr4, const int* __restrict__ adj4,
    const float* __restrict__ alx, const unsigned short* __restrict__ hb4,
    const float* __restrict__ bias, const float* __restrict__ maxsrc) {
  const int srct[4] = {0, 1, 0, 2};
  const int dstt[4] = {1, 0, 2, 0};
  int h = lane >> 3, e8 = lane & 7, ob = lane & 56;
  const int* rowptr = rowptr4 + r * (NN + 1);
  const int* adj = adj4 + (size_t)r * EE;
  const float* alsrc = alx + ((size_t)((g * 3 + srct[r]) * 8 + 2 * r) * NN) * 8;
  const float* aldst = alx + ((size_t)((g * 3 + dstt[r]) * 8 + 2 * r + 1) * NN) * 8;
  const unsigned short* hb = hb4 + (size_t)r * (NN * 256);

  int beg = rowptr[d], end = rowptr[d + 1];
  float adst = aldst[(size_t)d * 8 + h];
  // exact per-node upper bound of all segment logits (lrelu is monotone)
  float ub = maxsrc[(g * 4 + r) * 8 + h] + adst;
  ub = ub >= 0.f ? ub : 0.2f * ub;
  float es = alsrc[(size_t)d * 8 + h] + adst;
  es = es >= 0.f ? es : 0.2f * es;
  float wself = __expf(es - ub);
  float ssum = (e8 == 0) ? wself : 0.0f;         // self-loop, once per octet
  f32x4 hvs = ld_bf4(hb + (size_t)d * 256 + lane * 4);
  f32x4 acc;
#pragma unroll
  for (int i = 0; i < 4; ++i) acc[i] = wself * hvs[i];

  for (int j0 = beg; j0 < end; j0 += 8) {
    int j = j0 + e8;
    bool valid = j < end;
    int s = valid ? adj[j] : d;                  // clamp invalid to hot self row
    float t = alsrc[(size_t)s * 8 + h] + adst;
    t = t >= 0.f ? t : 0.2f * t;
    float w = valid ? __expf(t - ub) : 0.f;      // in (0,1], no rescale needed
    ssum += w;
#pragma unroll
    for (int e2 = 0; e2 < 8; ++e2) {
      int se = __shfl(s, ob + e2, 64);
      float we = __shfl(w, ob + e2, 64);
      f32x4 hv = ld_bf4(hb + (size_t)se * 256 + lane * 4);
#pragma unroll
      for (int i = 0; i < 4; ++i) acc[i] += we * hv[i];
    }
  }
  ssum += __shfl_xor(ssum, 1, 64);
  ssum += __shfl_xor(ssum, 2, 64);
  ssum += __shfl_xor(ssum, 4, 64);
  float inv = 1.f / ssum;
  f32x4 bv = *(const f32x4*)(bias + r * 256 + lane * 4);
  f32x4 res;
#pragma unroll
  for (int i = 0; i < 4; ++i) res[i] = acc[i] * inv + bv[i];
  return res;
}

// ---- all four relations per graph in one dispatch -------------------------
// y=0: r0 -> author; y=1: 0.5*(r1+r3) -> paper; y=2: r2 -> subject
__global__ __launch_bounds__(256) void k_agg4(
    const int* __restrict__ rowptr4, const int* __restrict__ adj4,
    const float* __restrict__ alx, const unsigned short* __restrict__ hb4,
    const float* __restrict__ bias, const float* __restrict__ maxsrc,
    float* __restrict__ out, int g) {
  int wave = threadIdx.x >> 6, lane = threadIdx.x & 63;
  int d = blockIdx.x * 4 + wave;
  int y = blockIdx.y;
  f32x4 res;
  int sec;
  if (y == 1) {
    f32x4 r1 = agg_one(1, g, d, lane, rowptr4, adj4, alx, hb4, bias, maxsrc);
    f32x4 r3 = agg_one(3, g, d, lane, rowptr4, adj4, alx, hb4, bias, maxsrc);
#pragma unroll
    for (int i = 0; i < 4; ++i) res[i] = 0.5f * (r1[i] + r3[i]);
    sec = 0;
  } else {
    int r = (y == 0) ? 0 : 2;
    res = agg_one(r, g, d, lane, rowptr4, adj4, alx, hb4, bias, maxsrc);
    sec = (y == 0) ? 1 : 2;
  }
  *(f32x4*)(out + ((size_t)(g * 3 + sec) * NN + d) * 256 + lane * 4) = res;
}

extern "C" void kernel_launch(void* const* d_in, const int* in_sizes, int n_in,
                              void* d_out, int out_size, void* d_ws, size_t ws_size,
                              hipStream_t stream) {
  (void)in_sizes; (void)n_in; (void)out_size; (void)ws_size;
  const float* x[6];
  for (int i = 0; i < 6; ++i) x[i] = (const float*)d_in[i];
  const float* W = (const float*)d_in[6];
  const float* att_src = (const float*)d_in[7];
  const float* att_dst = (const float*)d_in[8];
  const float* bias = (const float*)d_in[9];
  const int* ei[4] = {(const int*)d_in[10], (const int*)d_in[11],
                      (const int*)d_in[12], (const int*)d_in[13]};
  float* out = (float*)d_out;

  char* ws = (char*)d_ws;
  size_t off = 0;
  auto take = [&](size_t bytes) -> char* {
    char* p = ws + off;
    off += (bytes + 255) & ~(size_t)255;
    return p;
  };
  unsigned short* xb = (unsigned short*)take(6ull * NN * 256 * 2);    // 122.9 MB
  unsigned short* hb = (unsigned short*)take(4ull * NN * 256 * 2);    // 81.9 MB
  float* alx = (float*)take(6ull * NN * 64 * 4);                      // 61.4 MB
  unsigned short* wt2 = (unsigned short*)take(4ull * 8 * 256 * 32 * 2);
  float* weff = (float*)take(8ull * 256 * 8 * 4);
  unsigned short* weffb = (unsigned short*)take(8ull * 64 * 32 * 2);
  int* cnt = (int*)take(4ull * NN * 4);
  int* rowptr = (int*)take(4ull * (NN + 1) * 4);
  int* cursor = (int*)take(4ull * NN * 4);
  int* adj = (int*)take(4ull * EE * 4);
  float* pmax = (float*)take(8ull * 32 * 8 * 4);
  float* maxsrc = (float*)take(64ull * 4);

  k_convx<<<dim3(10000, 6), 256, 0, stream>>>(x[0], x[1], x[2], x[3], x[4], x[5], xb);
  k_wt2<<<dim3(1024), 256, 0, stream>>>(W, wt2);
  k_weff<<<dim3(64), 256, 0, stream>>>(W, att_src, att_dst, weff);
  k_weffb<<<dim3(64), 256, 0, stream>>>(weff, weffb);
  k_zero<<<dim3(625), 256, 0, stream>>>(cnt, 4 * NN);
  k_hist<<<dim3((EE + 255) / 256, 4), 256, 0, stream>>>(ei[0], ei[1], ei[2], ei[3], cnt);
  k_scan<<<dim3(4), 1024, 0, stream>>>(cnt, rowptr, cursor);
  k_scatter<<<dim3((EE + 255) / 256, 4), 256, 0, stream>>>(ei[0], ei[1], ei[2], ei[3], cursor, adj);
  k_algemm<<<dim3(625, 6), 256, 0, stream>>>(xb, weffb, alx);
  k_maxsrcp<<<dim3(8, 32), 256, 0, stream>>>(alx, pmax);
  k_maxfin<<<dim3(1), 64, 0, stream>>>(pmax, maxsrc);

  for (int g = 0; g < 2; ++g) {
    k_gemmb4<<<dim3(625, 4), 256, 0, stream>>>(xb, wt2, hb, g);
    k_agg4<<<dim3(10000, 3), 256, 0, stream>>>(rowptr, adj, alx, hb, bias, maxsrc, out, g);
  }
}

// Round 6
// 871.239 us; speedup vs baseline: 1.0168x; 1.0168x over previous
//
#include <hip/hip_runtime.h>

#define NN 40000
#define EE 400000

typedef short short8 __attribute__((ext_vector_type(8)));
typedef float f32x4 __attribute__((ext_vector_type(4)));
typedef unsigned short ushort4_ __attribute__((ext_vector_type(4)));

__device__ __forceinline__ unsigned short f2bf(float f) {
  unsigned int u = __float_as_uint(f);
  u = (u + 0x7FFFu + ((u >> 16) & 1u)) >> 16;
  return (unsigned short)u;
}

__device__ __forceinline__ short8 cvt8(f32x4 a, f32x4 b) {
  short8 r;
  r[0] = (short)f2bf(a[0]); r[1] = (short)f2bf(a[1]);
  r[2] = (short)f2bf(a[2]); r[3] = (short)f2bf(a[3]);
  r[4] = (short)f2bf(b[0]); r[5] = (short)f2bf(b[1]);
  r[6] = (short)f2bf(b[2]); r[7] = (short)f2bf(b[3]);
  return r;
}

__device__ __forceinline__ f32x4 ld_bf4(const unsigned short* p) {
  ushort4_ u = *(const ushort4_*)p;
  f32x4 r;
  r[0] = __uint_as_float((unsigned int)u[0] << 16);
  r[1] = __uint_as_float((unsigned int)u[1] << 16);
  r[2] = __uint_as_float((unsigned int)u[2] << 16);
  r[3] = __uint_as_float((unsigned int)u[3] << 16);
  return r;
}

// ---- W -> bf16, k-tiled transposed: wt2[r][kt][n][k0] = W[r][kt*32+k0][n] --
__global__ __launch_bounds__(256) void k_wt2(const float* __restrict__ W,
                                             unsigned short* __restrict__ wt2) {
  int idx = blockIdx.x * 256 + threadIdx.x;  // < 262144
  int k0 = idx & 31, n = (idx >> 5) & 255, kt = (idx >> 13) & 7, r = idx >> 16;
  float v = W[((size_t)(r * 256) + (kt * 32 + k0)) * 256 + n];
  wt2[idx] = f2bf(v);
}

// ---- weff[q][f][j] = sum_c W[r][f][j*32+c] * att[r][j][c], q = r*2+side ----
__global__ __launch_bounds__(256) void k_weff(const float* __restrict__ W,
                                              const float* __restrict__ asrc,
                                              const float* __restrict__ adst,
                                              float* __restrict__ weff) {
  int idx = blockIdx.x * 256 + threadIdx.x;  // < 16384
  int j = idx & 7, f = (idx >> 3) & 255, q = idx >> 11;
  int r = q >> 1, side = q & 1;
  const float* att = side ? adst : asrc;
  const float* wrow = W + ((size_t)(r * 256) + f) * 256 + j * 32;
  const float* arow = att + (r * 8 + j) * 32;
  float s = 0.f;
#pragma unroll
  for (int c = 0; c < 32; ++c) s += wrow[c] * arow[c];
  weff[idx] = s;
}

// ---- weff -> bf16 k-tiled B layout: weffb[kt][col][k0], col = q*8 + j ------
__global__ __launch_bounds__(256) void k_weffb(const float* __restrict__ weff,
                                               unsigned short* __restrict__ weffb) {
  int idx = blockIdx.x * 256 + threadIdx.x;  // < 16384
  int k0 = idx & 31, col = (idx >> 5) & 63, kt = idx >> 11;
  int q = col >> 3, j = col & 7;
  int f = kt * 32 + k0;
  weffb[idx] = f2bf(weff[(q * 256 + f) * 8 + j]);
}

// ---- CSR build ------------------------------------------------------------
__global__ __launch_bounds__(256) void k_zero(int* __restrict__ p, int n) {
  int i = blockIdx.x * 256 + threadIdx.x;
  if (i < n) p[i] = 0;
}

__global__ __launch_bounds__(256) void k_hist(
    const int* __restrict__ e0, const int* __restrict__ e1,
    const int* __restrict__ e2, const int* __restrict__ e3, int* __restrict__ cnt) {
  int r = blockIdx.y;
  const int* ei = (r == 0) ? e0 : (r == 1) ? e1 : (r == 2) ? e2 : e3;
  int e = blockIdx.x * 256 + threadIdx.x;
  if (e < EE) atomicAdd(&cnt[r * NN + ei[EE + e]], 1);
}

__global__ __launch_bounds__(1024) void k_scan(const int* __restrict__ cnt,
                                               int* __restrict__ rowptr,
                                               int* __restrict__ cursor) {
  int r = blockIdx.x;
  const int* c = cnt + r * NN;
  int* rp = rowptr + r * (NN + 1);
  int* cur = cursor + r * NN;
  __shared__ int part[1024];
  int t = threadIdx.x;
  const int per = 40;  // 1024*40 >= 40000
  int base = t * per;
  int sum = 0;
  for (int i = 0; i < per; ++i) { int idx = base + i; if (idx < NN) sum += c[idx]; }
  part[t] = sum;
  __syncthreads();
  for (int o = 1; o < 1024; o <<= 1) {
    int v = (t >= o) ? part[t - o] : 0;
    __syncthreads();
    part[t] += v;
    __syncthreads();
  }
  int run = part[t] - sum;  // exclusive prefix
  for (int i = 0; i < per; ++i) {
    int idx = base + i;
    if (idx < NN) { rp[idx] = run; cur[idx] = run; run += c[idx]; }
  }
  if (t == 1023) rp[NN] = part[1023];
}

__global__ __launch_bounds__(256) void k_scatter(
    const int* __restrict__ e0, const int* __restrict__ e1,
    const int* __restrict__ e2, const int* __restrict__ e3,
    int* __restrict__ cursor, int* __restrict__ adj) {
  int r = blockIdx.y;
  const int* ei = (r == 0) ? e0 : (r == 1) ? e1 : (r == 2) ? e2 : e3;
  int e = blockIdx.x * 256 + threadIdx.x;
  if (e < EE) {
    int s = ei[e], d = ei[EE + e];
    int pos = atomicAdd(&cursor[r * NN + d], 1);
    adj[(size_t)r * EE + pos] = s;
  }
}

// ---- fused: f32 x -> bf16 xb, plus logits alx[z][q][n][8] = xb @ weffb ----
__global__ __launch_bounds__(256) void k_algemm(
    const float* __restrict__ x0, const float* __restrict__ x1, const float* __restrict__ x2,
    const float* __restrict__ x3, const float* __restrict__ x4, const float* __restrict__ x5,
    const unsigned short* __restrict__ weffb,
    unsigned short* __restrict__ xb, float* __restrict__ alx) {
  __shared__ __attribute__((aligned(16))) unsigned short Alds[64][40];
  __shared__ __attribute__((aligned(16))) unsigned short Blds[64][40];
  int z = blockIdx.y;
  const float* xp;
  switch (z) { case 0: xp = x0; break; case 1: xp = x1; break; case 2: xp = x2; break;
               case 3: xp = x3; break; case 4: xp = x4; break; default: xp = x5; break; }
  unsigned short* xbp = xb + (size_t)z * (NN * 256);
  int tid = threadIdx.x;
  int wave = tid >> 6, lane = tid & 63;
  int l15 = lane & 15, l16 = lane >> 4;
  int row0 = blockIdx.x * 64;
  f32x4 acc[4] = {};
  int ar = tid >> 2, ac = (tid & 3) * 8;
  const float* aglob = xp + (size_t)(row0 + ar) * 256 + ac;
  unsigned short* xglob = xbp + (size_t)(row0 + ar) * 256 + ac;
  for (int kt = 0; kt < 8; ++kt) {
    f32x4 a0 = *(const f32x4*)(aglob + kt * 32);
    f32x4 a1 = *(const f32x4*)(aglob + kt * 32 + 4);
    short8 av = cvt8(a0, a1);
    *(short8*)(&Alds[ar][ac]) = av;
    *(short8*)(xglob + kt * 32) = av;
    short8 bv = *(const short8*)(weffb + kt * 2048 + tid * 8);
    *(short8*)(&Blds[tid >> 2][(tid & 3) * 8]) = bv;
    __syncthreads();
    short8 bf = *(const short8*)(&Blds[wave * 16 + l15][l16 * 8]);
#pragma unroll
    for (int mt = 0; mt < 4; ++mt) {
      short8 af = *(const short8*)(&Alds[mt * 16 + l15][l16 * 8]);
      acc[mt] = __builtin_amdgcn_mfma_f32_16x16x32_bf16(af, bf, acc[mt], 0, 0, 0);
    }
    __syncthreads();
  }
  int col = wave * 16 + l15;
  int q = col >> 3, jj = col & 7;
#pragma unroll
  for (int mt = 0; mt < 4; ++mt)
#pragma unroll
    for (int rr = 0; rr < 4; ++rr) {
      int row = row0 + mt * 16 + l16 * 4 + rr;
      alx[(((size_t)z * 8 + q) * NN + row) * 8 + jj] = acc[mt][rr];
    }
}

// ---- per-head global max of alsrc column, stage 1: 32 slices of 1250 ------
__global__ __launch_bounds__(256) void k_maxsrcp(const float* __restrict__ alx,
                                                 float* __restrict__ pmax) {
  const int srct[4] = {0, 1, 0, 2};
  int gr = blockIdx.x, slice = blockIdx.y;
  int g = gr >> 2, r = gr & 3;
  const float* col = alx + ((size_t)((g * 3 + srct[r]) * 8 + 2 * r) * NN) * 8;
  int t = threadIdx.x;
  int h = t & 7, chunk = t >> 3;  // 32 chunks
  float m = -1e30f;
  for (int nn = chunk; nn < 1250; nn += 32)
    m = fmaxf(m, col[(size_t)(slice * 1250 + nn) * 8 + h]);
  __shared__ float red[256];
  red[t] = m;
  __syncthreads();
  for (int o = 128; o >= 8; o >>= 1) {
    if (t < o) red[t] = fmaxf(red[t], red[t + o]);
    __syncthreads();
  }
  if (t < 8) pmax[(gr * 32 + slice) * 8 + t] = red[t];
}

__global__ __launch_bounds__(64) void k_maxfin(const float* __restrict__ pmax,
                                               float* __restrict__ maxsrc) {
  int t = threadIdx.x;  // 64 = 8 gr * 8 h
  int gr = t >> 3, h = t & 7;
  float m = -1e30f;
  for (int s = 0; s < 32; ++s) m = fmaxf(m, pmax[(gr * 32 + s) * 8 + h]);
  maxsrc[t] = m;
}

// ---- bf16 MFMA GEMM (batched over r): hb[r][40000][256] = bf16(xb @ W) ----
__global__ __launch_bounds__(256) void k_gemmb4(const unsigned short* __restrict__ xb,
                                                const unsigned short* __restrict__ wt2,
                                                unsigned short* __restrict__ hb4, int g) {
  __shared__ __attribute__((aligned(16))) unsigned short Alds[64][40];
  __shared__ __attribute__((aligned(16))) unsigned short Blds[256][40];
  const int srct[4] = {0, 1, 0, 2};
  int r = blockIdx.y;
  const unsigned short* xbp = xb + (size_t)(g * 3 + srct[r]) * (NN * 256);
  const unsigned short* wtp = wt2 + (size_t)r * (8 * 256 * 32);
  unsigned short* hbp = hb4 + (size_t)r * (NN * 256);
  int tid = threadIdx.x;
  int wave = tid >> 6, lane = tid & 63;
  int l15 = lane & 15, l16 = lane >> 4;
  int row0 = blockIdx.x * 64;
  f32x4 acc[4][4] = {};
  int ar = tid >> 2, ac = (tid & 3) * 8;
  const unsigned short* aglob = xbp + (size_t)(row0 + ar) * 256 + ac;
  for (int kt = 0; kt < 8; ++kt) {
    short8 av = *(const short8*)(aglob + kt * 32);
    *(short8*)(&Alds[ar][ac]) = av;
    const unsigned short* bsrc = wtp + kt * (256 * 32);
#pragma unroll
    for (int i = 0; i < 4; ++i) {
      int cidx = tid + 256 * i;
      short8 bv = *(const short8*)(bsrc + cidx * 8);
      *(short8*)(&Blds[cidx >> 2][(cidx & 3) * 8]) = bv;
    }
    __syncthreads();
    short8 af[4], bf[4];
#pragma unroll
    for (int mt = 0; mt < 4; ++mt) af[mt] = *(const short8*)(&Alds[mt * 16 + l15][l16 * 8]);
#pragma unroll
    for (int nt = 0; nt < 4; ++nt) bf[nt] = *(const short8*)(&Blds[wave * 64 + nt * 16 + l15][l16 * 8]);
#pragma unroll
    for (int mt = 0; mt < 4; ++mt)
#pragma unroll
      for (int nt = 0; nt < 4; ++nt)
        acc[mt][nt] = __builtin_amdgcn_mfma_f32_16x16x32_bf16(af[mt], bf[nt], acc[mt][nt], 0, 0, 0);
    __syncthreads();
  }
#pragma unroll
  for (int mt = 0; mt < 4; ++mt)
#pragma unroll
    for (int nt = 0; nt < 4; ++nt)
#pragma unroll
      for (int rr = 0; rr < 4; ++rr)
        hbp[(size_t)(row0 + mt * 16 + l16 * 4 + rr) * 256 + wave * 64 + nt * 16 + l15] =
            f2bf(acc[mt][nt][rr]);
}

// ---- one-relation softmax aggregation, upper-bound shift ------------------
__device__ __forceinline__ f32x4 agg_one(
    int r, int g, int d, int lane,
    const int* __restrict__ rowptr4, const int* __restrict__ adj4,
    const float* __restrict__ alx, const unsigned short* __restrict__ hb4,
    const float* __restrict__ bias, const float* __restrict__ maxsrc) {
  const int srct[4] = {0, 1, 0, 2};
  const int dstt[4] = {1, 0, 2, 0};
  int h = lane >> 3, e8 = lane & 7, ob = lane & 56;
  const int* rowptr = rowptr4 + r * (NN + 1);
  const int* adj = adj4 + (size_t)r * EE;
  const float* alsrc = alx + ((size_t)((g * 3 + srct[r]) * 8 + 2 * r) * NN) * 8;
  const float* aldst = alx + ((size_t)((g * 3 + dstt[r]) * 8 + 2 * r + 1) * NN) * 8;
  const unsigned short* hb = hb4 + (size_t)r * (NN * 256);

  int beg = rowptr[d], end = rowptr[d + 1];
  float adst = aldst[(size_t)d * 8 + h];
  float ub = maxsrc[(g * 4 + r) * 8 + h] + adst;  // exact segment upper bound
  ub = ub >= 0.f ? ub : 0.2f * ub;
  float es = alsrc[(size_t)d * 8 + h] + adst;
  es = es >= 0.f ? es : 0.2f * es;
  float wself = __expf(es - ub);
  float ssum = (e8 == 0) ? wself : 0.0f;
  f32x4 hvs = ld_bf4(hb + (size_t)d * 256 + lane * 4);
  f32x4 acc;
#pragma unroll
  for (int i = 0; i < 4; ++i) acc[i] = wself * hvs[i];

  for (int j0 = beg; j0 < end; j0 += 8) {
    int j = j0 + e8;
    bool valid = j < end;
    int s = valid ? adj[j] : d;
    float t = alsrc[(size_t)s * 8 + h] + adst;
    t = t >= 0.f ? t : 0.2f * t;
    float w = valid ? __expf(t - ub) : 0.f;
    ssum += w;
#pragma unroll
    for (int e2 = 0; e2 < 8; ++e2) {
      int se = __shfl(s, ob + e2, 64);
      float we = __shfl(w, ob + e2, 64);
      f32x4 hv = ld_bf4(hb + (size_t)se * 256 + lane * 4);
#pragma unroll
      for (int i = 0; i < 4; ++i) acc[i] += we * hv[i];
    }
  }
  ssum += __shfl_xor(ssum, 1, 64);
  ssum += __shfl_xor(ssum, 2, 64);
  ssum += __shfl_xor(ssum, 4, 64);
  float inv = 1.f / ssum;
  f32x4 bv = *(const f32x4*)(bias + r * 256 + lane * 4);
  f32x4 res;
#pragma unroll
  for (int i = 0; i < 4; ++i) res[i] = acc[i] * inv + bv[i];
  return res;
}

// ---- persistent-wave aggregation: 1875 co-resident blocks, 16 items/wave --
// item = y*NN + d; y=0: r0->author, y=1: 0.5*(r1+r3)->paper, y=2: r2->subject
#define AGG_BLOCKS 1875
__global__ __launch_bounds__(256) void k_agg5(
    const int* __restrict__ rowptr4, const int* __restrict__ adj4,
    const float* __restrict__ alx, const unsigned short* __restrict__ hb4,
    const float* __restrict__ bias, const float* __restrict__ maxsrc,
    float* __restrict__ out, int g) {
  int lane = threadIdx.x & 63;
  int wgid = (blockIdx.x * 256 + (int)threadIdx.x) >> 6;
  const int NWV = AGG_BLOCKS * 4;
  for (int item = wgid; item < 3 * NN; item += NWV) {
    int y = item / NN;
    int d = item - y * NN;
    f32x4 res;
    int sec;
    if (y == 1) {
      f32x4 r1 = agg_one(1, g, d, lane, rowptr4, adj4, alx, hb4, bias, maxsrc);
      f32x4 r3 = agg_one(3, g, d, lane, rowptr4, adj4, alx, hb4, bias, maxsrc);
#pragma unroll
      for (int i = 0; i < 4; ++i) res[i] = 0.5f * (r1[i] + r3[i]);
      sec = 0;
    } else {
      int r = (y == 0) ? 0 : 2;
      res = agg_one(r, g, d, lane, rowptr4, adj4, alx, hb4, bias, maxsrc);
      sec = (y == 0) ? 1 : 2;
    }
    f32x4* op = (f32x4*)(out + ((size_t)(g * 3 + sec) * NN + d) * 256 + lane * 4);
    __builtin_nontemporal_store(res, op);
  }
}

extern "C" void kernel_launch(void* const* d_in, const int* in_sizes, int n_in,
                              void* d_out, int out_size, void* d_ws, size_t ws_size,
                              hipStream_t stream) {
  (void)in_sizes; (void)n_in; (void)out_size; (void)ws_size;
  const float* x[6];
  for (int i = 0; i < 6; ++i) x[i] = (const float*)d_in[i];
  const float* W = (const float*)d_in[6];
  const float* att_src = (const float*)d_in[7];
  const float* att_dst = (const float*)d_in[8];
  const float* bias = (const float*)d_in[9];
  const int* ei[4] = {(const int*)d_in[10], (const int*)d_in[11],
                      (const int*)d_in[12], (const int*)d_in[13]};
  float* out = (float*)d_out;

  char* ws = (char*)d_ws;
  size_t off = 0;
  auto take = [&](size_t bytes) -> char* {
    char* p = ws + off;
    off += (bytes + 255) & ~(size_t)255;
    return p;
  };
  unsigned short* xb = (unsigned short*)take(6ull * NN * 256 * 2);    // 122.9 MB
  unsigned short* hb = (unsigned short*)take(4ull * NN * 256 * 2);    // 81.9 MB
  float* alx = (float*)take(6ull * NN * 64 * 4);                      // 61.4 MB
  unsigned short* wt2 = (unsigned short*)take(4ull * 8 * 256 * 32 * 2);
  float* weff = (float*)take(8ull * 256 * 8 * 4);
  unsigned short* weffb = (unsigned short*)take(8ull * 64 * 32 * 2);
  int* cnt = (int*)take(4ull * NN * 4);
  int* rowptr = (int*)take(4ull * (NN + 1) * 4);
  int* cursor = (int*)take(4ull * NN * 4);
  int* adj = (int*)take(4ull * EE * 4);
  float* pmax = (float*)take(8ull * 32 * 8 * 4);
  float* maxsrc = (float*)take(64ull * 4);

  k_wt2<<<dim3(1024), 256, 0, stream>>>(W, wt2);
  k_weff<<<dim3(64), 256, 0, stream>>>(W, att_src, att_dst, weff);
  k_weffb<<<dim3(64), 256, 0, stream>>>(weff, weffb);
  k_zero<<<dim3(625), 256, 0, stream>>>(cnt, 4 * NN);
  k_hist<<<dim3((EE + 255) / 256, 4), 256, 0, stream>>>(ei[0], ei[1], ei[2], ei[3], cnt);
  k_scan<<<dim3(4), 1024, 0, stream>>>(cnt, rowptr, cursor);
  k_scatter<<<dim3((EE + 255) / 256, 4), 256, 0, stream>>>(ei[0], ei[1], ei[2], ei[3], cursor, adj);
  k_algemm<<<dim3(625, 6), 256, 0, stream>>>(x[0], x[1], x[2], x[3], x[4], x[5],
                                             weffb, xb, alx);
  k_maxsrcp<<<dim3(8, 32), 256, 0, stream>>>(alx, pmax);
  k_maxfin<<<dim3(1), 64, 0, stream>>>(pmax, maxsrc);

  for (int g = 0; g < 2; ++g) {
    k_gemmb4<<<dim3(625, 4), 256, 0, stream>>>(xb, wt2, hb, g);
    k_agg5<<<dim3(AGG_BLOCKS), 256, 0, stream>>>(rowptr, adj, alx, hb, bias, maxsrc, out, g);
  }
}

// Round 7
// 844.870 us; speedup vs baseline: 1.0485x; 1.0312x over previous
//
#include <hip/hip_runtime.h>

#define NN 40000
#define EE 400000

typedef short short8 __attribute__((ext_vector_type(8)));
typedef float f32x4 __attribute__((ext_vector_type(4)));
typedef unsigned short ushort4_ __attribute__((ext_vector_type(4)));

__device__ __forceinline__ unsigned short f2bf(float f) {
  unsigned int u = __float_as_uint(f);
  u = (u + 0x7FFFu + ((u >> 16) & 1u)) >> 16;
  return (unsigned short)u;
}

__device__ __forceinline__ short8 cvt8(f32x4 a, f32x4 b) {
  short8 r;
  r[0] = (short)f2bf(a[0]); r[1] = (short)f2bf(a[1]);
  r[2] = (short)f2bf(a[2]); r[3] = (short)f2bf(a[3]);
  r[4] = (short)f2bf(b[0]); r[5] = (short)f2bf(b[1]);
  r[6] = (short)f2bf(b[2]); r[7] = (short)f2bf(b[3]);
  return r;
}

__device__ __forceinline__ f32x4 ld_bf4(const unsigned short* p) {
  ushort4_ u = *(const ushort4_*)p;
  f32x4 r;
  r[0] = __uint_as_float((unsigned int)u[0] << 16);
  r[1] = __uint_as_float((unsigned int)u[1] << 16);
  r[2] = __uint_as_float((unsigned int)u[2] << 16);
  r[3] = __uint_as_float((unsigned int)u[3] << 16);
  return r;
}

// ---- W -> bf16, k-tiled transposed: wt2[r][kt][n][k0] = W[r][kt*32+k0][n] --
__global__ __launch_bounds__(256) void k_wt2(const float* __restrict__ W,
                                             unsigned short* __restrict__ wt2) {
  int idx = blockIdx.x * 256 + threadIdx.x;  // < 262144
  int k0 = idx & 31, n = (idx >> 5) & 255, kt = (idx >> 13) & 7, r = idx >> 16;
  float v = W[((size_t)(r * 256) + (kt * 32 + k0)) * 256 + n];
  wt2[idx] = f2bf(v);
}

// ---- weff[q][f][j] = sum_c W[r][f][j*32+c] * att[r][j][c], q = r*2+side ----
__global__ __launch_bounds__(256) void k_weff(const float* __restrict__ W,
                                              const float* __restrict__ asrc,
                                              const float* __restrict__ adst,
                                              float* __restrict__ weff) {
  int idx = blockIdx.x * 256 + threadIdx.x;  // < 16384
  int j = idx & 7, f = (idx >> 3) & 255, q = idx >> 11;
  int r = q >> 1, side = q & 1;
  const float* att = side ? adst : asrc;
  const float* wrow = W + ((size_t)(r * 256) + f) * 256 + j * 32;
  const float* arow = att + (r * 8 + j) * 32;
  float s = 0.f;
#pragma unroll
  for (int c = 0; c < 32; ++c) s += wrow[c] * arow[c];
  weff[idx] = s;
}

// ---- weff -> bf16 k-tiled B layout: weffb[kt][col][k0], col = q*8 + j ------
__global__ __launch_bounds__(256) void k_weffb(const float* __restrict__ weff,
                                               unsigned short* __restrict__ weffb) {
  int idx = blockIdx.x * 256 + threadIdx.x;  // < 16384
  int k0 = idx & 31, col = (idx >> 5) & 63, kt = idx >> 11;
  int q = col >> 3, j = col & 7;
  int f = kt * 32 + k0;
  weffb[idx] = f2bf(weff[(q * 256 + f) * 8 + j]);
}

// ---- CSR build ------------------------------------------------------------
__global__ __launch_bounds__(256) void k_zero(int* __restrict__ p, int n) {
  int i = blockIdx.x * 256 + threadIdx.x;
  if (i < n) p[i] = 0;
}

__global__ __launch_bounds__(256) void k_hist(
    const int* __restrict__ e0, const int* __restrict__ e1,
    const int* __restrict__ e2, const int* __restrict__ e3, int* __restrict__ cnt) {
  int r = blockIdx.y;
  const int* ei = (r == 0) ? e0 : (r == 1) ? e1 : (r == 2) ? e2 : e3;
  int e = blockIdx.x * 256 + threadIdx.x;
  if (e < EE) atomicAdd(&cnt[r * NN + ei[EE + e]], 1);
}

__global__ __launch_bounds__(1024) void k_scan(const int* __restrict__ cnt,
                                               int* __restrict__ rowptr,
                                               int* __restrict__ cursor) {
  int r = blockIdx.x;
  const int* c = cnt + r * NN;
  int* rp = rowptr + r * (NN + 1);
  int* cur = cursor + r * NN;
  __shared__ int part[1024];
  int t = threadIdx.x;
  const int per = 40;  // 1024*40 >= 40000
  int base = t * per;
  int sum = 0;
  for (int i = 0; i < per; ++i) { int idx = base + i; if (idx < NN) sum += c[idx]; }
  part[t] = sum;
  __syncthreads();
  for (int o = 1; o < 1024; o <<= 1) {
    int v = (t >= o) ? part[t - o] : 0;
    __syncthreads();
    part[t] += v;
    __syncthreads();
  }
  int run = part[t] - sum;  // exclusive prefix
  for (int i = 0; i < per; ++i) {
    int idx = base + i;
    if (idx < NN) { rp[idx] = run; cur[idx] = run; run += c[idx]; }
  }
  if (t == 1023) rp[NN] = part[1023];
}

__global__ __launch_bounds__(256) void k_scatter(
    const int* __restrict__ e0, const int* __restrict__ e1,
    const int* __restrict__ e2, const int* __restrict__ e3,
    int* __restrict__ cursor, int* __restrict__ adj) {
  int r = blockIdx.y;
  const int* ei = (r == 0) ? e0 : (r == 1) ? e1 : (r == 2) ? e2 : e3;
  int e = blockIdx.x * 256 + threadIdx.x;
  if (e < EE) {
    int s = ei[e], d = ei[EE + e];
    int pos = atomicAdd(&cursor[r * NN + d], 1);
    adj[(size_t)r * EE + pos] = s;
  }
}

// ---- logits: alx[z][q][n][8] = bf16(x[z]) @ weffb (f32 A staged in-kernel) -
__global__ __launch_bounds__(256) void k_algemm(
    const float* __restrict__ x0, const float* __restrict__ x1, const float* __restrict__ x2,
    const float* __restrict__ x3, const float* __restrict__ x4, const float* __restrict__ x5,
    const unsigned short* __restrict__ weffb, float* __restrict__ alx) {
  __shared__ __attribute__((aligned(16))) unsigned short Alds[64][40];
  __shared__ __attribute__((aligned(16))) unsigned short Blds[64][40];
  int z = blockIdx.y;
  const float* xp;
  switch (z) { case 0: xp = x0; break; case 1: xp = x1; break; case 2: xp = x2; break;
               case 3: xp = x3; break; case 4: xp = x4; break; default: xp = x5; break; }
  int tid = threadIdx.x;
  int wave = tid >> 6, lane = tid & 63;
  int l15 = lane & 15, l16 = lane >> 4;
  int row0 = blockIdx.x * 64;
  f32x4 acc[4] = {};
  int ar = tid >> 2, ac = (tid & 3) * 8;
  const float* aglob = xp + (size_t)(row0 + ar) * 256 + ac;
  for (int kt = 0; kt < 8; ++kt) {
    f32x4 a0 = *(const f32x4*)(aglob + kt * 32);
    f32x4 a1 = *(const f32x4*)(aglob + kt * 32 + 4);
    *(short8*)(&Alds[ar][ac]) = cvt8(a0, a1);
    short8 bv = *(const short8*)(weffb + kt * 2048 + tid * 8);
    *(short8*)(&Blds[tid >> 2][(tid & 3) * 8]) = bv;
    __syncthreads();
    short8 bf = *(const short8*)(&Blds[wave * 16 + l15][l16 * 8]);
#pragma unroll
    for (int mt = 0; mt < 4; ++mt) {
      short8 af = *(const short8*)(&Alds[mt * 16 + l15][l16 * 8]);
      acc[mt] = __builtin_amdgcn_mfma_f32_16x16x32_bf16(af, bf, acc[mt], 0, 0, 0);
    }
    __syncthreads();
  }
  int col = wave * 16 + l15;
  int q = col >> 3, jj = col & 7;
#pragma unroll
  for (int mt = 0; mt < 4; ++mt)
#pragma unroll
    for (int rr = 0; rr < 4; ++rr) {
      int row = row0 + mt * 16 + l16 * 4 + rr;
      alx[(((size_t)z * 8 + q) * NN + row) * 8 + jj] = acc[mt][rr];
    }
}

// ---- per-head global max of alsrc column, stage 1: 32 slices of 1250 ------
__global__ __launch_bounds__(256) void k_maxsrcp(const float* __restrict__ alx,
                                                 float* __restrict__ pmax) {
  const int srct[4] = {0, 1, 0, 2};
  int gr = blockIdx.x, slice = blockIdx.y;
  int g = gr >> 2, r = gr & 3;
  const float* col = alx + ((size_t)((g * 3 + srct[r]) * 8 + 2 * r) * NN) * 8;
  int t = threadIdx.x;
  int h = t & 7, chunk = t >> 3;  // 32 chunks
  float m = -1e30f;
  for (int nn = chunk; nn < 1250; nn += 32)
    m = fmaxf(m, col[(size_t)(slice * 1250 + nn) * 8 + h]);
  __shared__ float red[256];
  red[t] = m;
  __syncthreads();
  for (int o = 128; o >= 8; o >>= 1) {
    if (t < o) red[t] = fmaxf(red[t], red[t + o]);
    __syncthreads();
  }
  if (t < 8) pmax[(gr * 32 + slice) * 8 + t] = red[t];
}

__global__ __launch_bounds__(64) void k_maxfin(const float* __restrict__ pmax,
                                               float* __restrict__ maxsrc) {
  int t = threadIdx.x;  // 64 = 8 gr * 8 h
  int gr = t >> 3, h = t & 7;
  float m = -1e30f;
  for (int s = 0; s < 32; ++s) m = fmaxf(m, pmax[(gr * 32 + s) * 8 + h]);
  maxsrc[t] = m;
}

// ---- bf16 MFMA GEMM, all 8 (g,r): hb8[g*4+r][40000][256] = bf16(x @ W) ----
__global__ __launch_bounds__(256) void k_gemmb8(
    const float* __restrict__ x0, const float* __restrict__ x1, const float* __restrict__ x2,
    const float* __restrict__ x3, const float* __restrict__ x4, const float* __restrict__ x5,
    const unsigned short* __restrict__ wt2, unsigned short* __restrict__ hb8) {
  __shared__ __attribute__((aligned(16))) unsigned short Alds[64][40];
  __shared__ __attribute__((aligned(16))) unsigned short Blds[256][40];
  const int srct[4] = {0, 1, 0, 2};
  int y = blockIdx.y;  // g*4 + r
  int g = y >> 2, r = y & 3;
  int t6 = g * 3 + srct[r];
  const float* xp;
  switch (t6) { case 0: xp = x0; break; case 1: xp = x1; break; case 2: xp = x2; break;
                case 3: xp = x3; break; case 4: xp = x4; break; default: xp = x5; break; }
  const unsigned short* wtp = wt2 + (size_t)r * (8 * 256 * 32);
  unsigned short* hbp = hb8 + (size_t)y * (NN * 256);
  int tid = threadIdx.x;
  int wave = tid >> 6, lane = tid & 63;
  int l15 = lane & 15, l16 = lane >> 4;
  int row0 = blockIdx.x * 64;
  f32x4 acc[4][4] = {};
  int ar = tid >> 2, ac = (tid & 3) * 8;
  const float* aglob = xp + (size_t)(row0 + ar) * 256 + ac;
  for (int kt = 0; kt < 8; ++kt) {
    f32x4 a0 = *(const f32x4*)(aglob + kt * 32);
    f32x4 a1 = *(const f32x4*)(aglob + kt * 32 + 4);
    *(short8*)(&Alds[ar][ac]) = cvt8(a0, a1);
    const unsigned short* bsrc = wtp + kt * (256 * 32);
#pragma unroll
    for (int i = 0; i < 4; ++i) {
      int cidx = tid + 256 * i;
      short8 bv = *(const short8*)(bsrc + cidx * 8);
      *(short8*)(&Blds[cidx >> 2][(cidx & 3) * 8]) = bv;
    }
    __syncthreads();
    short8 af[4], bf[4];
#pragma unroll
    for (int mt = 0; mt < 4; ++mt) af[mt] = *(const short8*)(&Alds[mt * 16 + l15][l16 * 8]);
#pragma unroll
    for (int nt = 0; nt < 4; ++nt) bf[nt] = *(const short8*)(&Blds[wave * 64 + nt * 16 + l15][l16 * 8]);
#pragma unroll
    for (int mt = 0; mt < 4; ++mt)
#pragma unroll
      for (int nt = 0; nt < 4; ++nt)
        acc[mt][nt] = __builtin_amdgcn_mfma_f32_16x16x32_bf16(af[mt], bf[nt], acc[mt][nt], 0, 0, 0);
    __syncthreads();
  }
#pragma unroll
  for (int mt = 0; mt < 4; ++mt)
#pragma unroll
    for (int nt = 0; nt < 4; ++nt)
#pragma unroll
      for (int rr = 0; rr < 4; ++rr)
        hbp[(size_t)(row0 + mt * 16 + l16 * 4 + rr) * 256 + wave * 64 + nt * 16 + l15] =
            f2bf(acc[mt][nt][rr]);
}

// ---- one-relation aggregation for BOTH graphs (shared edge structure) -----
// lane layout: head h = lane>>3, edge slot e8 = lane&7
__device__ __forceinline__ void agg_one2(
    int r, int d, int lane,
    const int* __restrict__ rowptr4, const int* __restrict__ adj4,
    const float* __restrict__ alx, const unsigned short* __restrict__ hb8,
    const float* __restrict__ maxsrc, f32x4& o0, f32x4& o1) {
  const int srct[4] = {0, 1, 0, 2};
  const int dstt[4] = {1, 0, 2, 0};
  int h = lane >> 3, e8 = lane & 7, ob = lane & 56;
  const int* rowptr = rowptr4 + r * (NN + 1);
  const int* adj = adj4 + (size_t)r * EE;
  const float* as0 = alx + ((size_t)((0 + srct[r]) * 8 + 2 * r) * NN) * 8;
  const float* ad0 = alx + ((size_t)((0 + dstt[r]) * 8 + 2 * r + 1) * NN) * 8;
  const float* as1 = alx + ((size_t)((3 + srct[r]) * 8 + 2 * r) * NN) * 8;
  const float* ad1 = alx + ((size_t)((3 + dstt[r]) * 8 + 2 * r + 1) * NN) * 8;
  const unsigned short* hb0 = hb8 + (size_t)r * (NN * 256);
  const unsigned short* hb1 = hb8 + (size_t)(4 + r) * (NN * 256);

  int beg = rowptr[d], end = rowptr[d + 1];
  float adst0 = ad0[(size_t)d * 8 + h];
  float adst1 = ad1[(size_t)d * 8 + h];
  float ub0 = maxsrc[r * 8 + h] + adst0;          // exact segment upper bound
  ub0 = ub0 >= 0.f ? ub0 : 0.2f * ub0;
  float ub1 = maxsrc[(4 + r) * 8 + h] + adst1;
  ub1 = ub1 >= 0.f ? ub1 : 0.2f * ub1;
  float es0 = as0[(size_t)d * 8 + h] + adst0;
  es0 = es0 >= 0.f ? es0 : 0.2f * es0;
  float es1 = as1[(size_t)d * 8 + h] + adst1;
  es1 = es1 >= 0.f ? es1 : 0.2f * es1;
  float ws0 = __expf(es0 - ub0), ws1 = __expf(es1 - ub1);
  float ssum0 = (e8 == 0) ? ws0 : 0.0f;
  float ssum1 = (e8 == 0) ? ws1 : 0.0f;
  f32x4 hv0 = ld_bf4(hb0 + (size_t)d * 256 + lane * 4);
  f32x4 hv1 = ld_bf4(hb1 + (size_t)d * 256 + lane * 4);
  f32x4 acc0, acc1;
#pragma unroll
  for (int i = 0; i < 4; ++i) { acc0[i] = ws0 * hv0[i]; acc1[i] = ws1 * hv1[i]; }

  for (int j0 = beg; j0 < end; j0 += 8) {
    int j = j0 + e8;
    bool valid = j < end;
    int s = valid ? adj[j] : d;
    float t0 = as0[(size_t)s * 8 + h] + adst0;
    t0 = t0 >= 0.f ? t0 : 0.2f * t0;
    float t1 = as1[(size_t)s * 8 + h] + adst1;
    t1 = t1 >= 0.f ? t1 : 0.2f * t1;
    float w0 = valid ? __expf(t0 - ub0) : 0.f;
    float w1 = valid ? __expf(t1 - ub1) : 0.f;
    ssum0 += w0;
    ssum1 += w1;
#pragma unroll
    for (int e2 = 0; e2 < 8; ++e2) {
      int se = __shfl(s, ob + e2, 64);
      float w0e = __shfl(w0, ob + e2, 64);
      float w1e = __shfl(w1, ob + e2, 64);
      f32x4 g0 = ld_bf4(hb0 + (size_t)se * 256 + lane * 4);
      f32x4 g1 = ld_bf4(hb1 + (size_t)se * 256 + lane * 4);
#pragma unroll
      for (int i = 0; i < 4; ++i) { acc0[i] += w0e * g0[i]; acc1[i] += w1e * g1[i]; }
    }
  }
  ssum0 += __shfl_xor(ssum0, 1, 64);
  ssum0 += __shfl_xor(ssum0, 2, 64);
  ssum0 += __shfl_xor(ssum0, 4, 64);
  ssum1 += __shfl_xor(ssum1, 1, 64);
  ssum1 += __shfl_xor(ssum1, 2, 64);
  ssum1 += __shfl_xor(ssum1, 4, 64);
  float i0 = 1.f / ssum0, i1 = 1.f / ssum1;
#pragma unroll
  for (int i = 0; i < 4; ++i) { o0[i] = acc0[i] * i0; o1[i] = acc1[i] * i1; }
}

// ---- persistent-wave aggregation, both graphs per item --------------------
// item = y*NN + d; y=0: r0->author, y=1: 0.5*(r1+r3)->paper, y=2: r2->subject
#define AGG_BLOCKS 1875
__global__ __launch_bounds__(256) void k_agg6(
    const int* __restrict__ rowptr4, const int* __restrict__ adj4,
    const float* __restrict__ alx, const unsigned short* __restrict__ hb8,
    const float* __restrict__ bias, const float* __restrict__ maxsrc,
    float* __restrict__ out) {
  int lane = threadIdx.x & 63;
  int wgid = (blockIdx.x * 256 + (int)threadIdx.x) >> 6;
  const int NWV = AGG_BLOCKS * 4;
  for (int item = wgid; item < 3 * NN; item += NWV) {
    int y = item / NN;
    int d = item - y * NN;
    f32x4 r0g0, r0g1, r1g0, r1g1;
    int sec, rb;
    if (y == 1) {
      agg_one2(1, d, lane, rowptr4, adj4, alx, hb8, maxsrc, r0g0, r0g1);
      agg_one2(3, d, lane, rowptr4, adj4, alx, hb8, maxsrc, r1g0, r1g1);
      f32x4 b1 = *(const f32x4*)(bias + 1 * 256 + lane * 4);
      f32x4 b3 = *(const f32x4*)(bias + 3 * 256 + lane * 4);
#pragma unroll
      for (int i = 0; i < 4; ++i) {
        r0g0[i] = 0.5f * (r0g0[i] + b1[i] + r1g0[i] + b3[i]);
        r0g1[i] = 0.5f * (r0g1[i] + b1[i] + r1g1[i] + b3[i]);
      }
      sec = 0;
    } else {
      int r = (y == 0) ? 0 : 2;
      agg_one2(r, d, lane, rowptr4, adj4, alx, hb8, maxsrc, r0g0, r0g1);
      f32x4 bv = *(const f32x4*)(bias + r * 256 + lane * 4);
#pragma unroll
      for (int i = 0; i < 4; ++i) { r0g0[i] += bv[i]; r0g1[i] += bv[i]; }
      sec = (y == 0) ? 1 : 2;
    }
    f32x4* op0 = (f32x4*)(out + ((size_t)(0 + sec) * NN + d) * 256 + lane * 4);
    f32x4* op1 = (f32x4*)(out + ((size_t)(3 + sec) * NN + d) * 256 + lane * 4);
    __builtin_nontemporal_store(r0g0, op0);
    __builtin_nontemporal_store(r0g1, op1);
  }
}

extern "C" void kernel_launch(void* const* d_in, const int* in_sizes, int n_in,
                              void* d_out, int out_size, void* d_ws, size_t ws_size,
                              hipStream_t stream) {
  (void)in_sizes; (void)n_in; (void)out_size; (void)ws_size;
  const float* x[6];
  for (int i = 0; i < 6; ++i) x[i] = (const float*)d_in[i];
  const float* W = (const float*)d_in[6];
  const float* att_src = (const float*)d_in[7];
  const float* att_dst = (const float*)d_in[8];
  const float* bias = (const float*)d_in[9];
  const int* ei[4] = {(const int*)d_in[10], (const int*)d_in[11],
                      (const int*)d_in[12], (const int*)d_in[13]};
  float* out = (float*)d_out;

  char* ws = (char*)d_ws;
  size_t off = 0;
  auto take = [&](size_t bytes) -> char* {
    char* p = ws + off;
    off += (bytes + 255) & ~(size_t)255;
    return p;
  };
  unsigned short* hb8 = (unsigned short*)take(8ull * NN * 256 * 2);   // 163.8 MB
  float* alx = (float*)take(6ull * NN * 64 * 4);                      // 61.4 MB
  unsigned short* wt2 = (unsigned short*)take(4ull * 8 * 256 * 32 * 2);
  float* weff = (float*)take(8ull * 256 * 8 * 4);
  unsigned short* weffb = (unsigned short*)take(8ull * 64 * 32 * 2);
  int* cnt = (int*)take(4ull * NN * 4);
  int* rowptr = (int*)take(4ull * (NN + 1) * 4);
  int* cursor = (int*)take(4ull * NN * 4);
  int* adj = (int*)take(4ull * EE * 4);
  float* pmax = (float*)take(8ull * 32 * 8 * 4);
  float* maxsrc = (float*)take(64ull * 4);

  k_wt2<<<dim3(1024), 256, 0, stream>>>(W, wt2);
  k_weff<<<dim3(64), 256, 0, stream>>>(W, att_src, att_dst, weff);
  k_weffb<<<dim3(64), 256, 0, stream>>>(weff, weffb);
  k_zero<<<dim3(625), 256, 0, stream>>>(cnt, 4 * NN);
  k_hist<<<dim3((EE + 255) / 256, 4), 256, 0, stream>>>(ei[0], ei[1], ei[2], ei[3], cnt);
  k_scan<<<dim3(4), 1024, 0, stream>>>(cnt, rowptr, cursor);
  k_scatter<<<dim3((EE + 255) / 256, 4), 256, 0, stream>>>(ei[0], ei[1], ei[2], ei[3], cursor, adj);
  k_algemm<<<dim3(625, 6), 256, 0, stream>>>(x[0], x[1], x[2], x[3], x[4], x[5],
                                             weffb, alx);
  k_maxsrcp<<<dim3(8, 32), 256, 0, stream>>>(alx, pmax);
  k_maxfin<<<dim3(1), 64, 0, stream>>>(pmax, maxsrc);
  k_gemmb8<<<dim3(625, 8), 256, 0, stream>>>(x[0], x[1], x[2], x[3], x[4], x[5],
                                             wt2, hb8);
  k_agg6<<<dim3(AGG_BLOCKS), 256, 0, stream>>>(rowptr, adj, alx, hb8, bias, maxsrc, out);
}

// Round 8
// 814.550 us; speedup vs baseline: 1.0876x; 1.0372x over previous
//
#include <hip/hip_runtime.h>

#define NN 40000
#define EE 400000

typedef short short8 __attribute__((ext_vector_type(8)));
typedef float f32x4 __attribute__((ext_vector_type(4)));
typedef unsigned short ushort4_ __attribute__((ext_vector_type(4)));

__device__ __forceinline__ unsigned short f2bf(float f) {
  unsigned int u = __float_as_uint(f);
  u = (u + 0x7FFFu + ((u >> 16) & 1u)) >> 16;
  return (unsigned short)u;
}

__device__ __forceinline__ short8 cvt8(f32x4 a, f32x4 b) {
  short8 r;
  r[0] = (short)f2bf(a[0]); r[1] = (short)f2bf(a[1]);
  r[2] = (short)f2bf(a[2]); r[3] = (short)f2bf(a[3]);
  r[4] = (short)f2bf(b[0]); r[5] = (short)f2bf(b[1]);
  r[6] = (short)f2bf(b[2]); r[7] = (short)f2bf(b[3]);
  return r;
}

__device__ __forceinline__ f32x4 ld_bf4(const unsigned short* p) {
  ushort4_ u = *(const ushort4_*)p;
  f32x4 r;
  r[0] = __uint_as_float((unsigned int)u[0] << 16);
  r[1] = __uint_as_float((unsigned int)u[1] << 16);
  r[2] = __uint_as_float((unsigned int)u[2] << 16);
  r[3] = __uint_as_float((unsigned int)u[3] << 16);
  return r;
}

// ---- W -> bf16, k-tiled transposed: wt2[r][kt][n][k0] = W[r][kt*32+k0][n] --
__global__ __launch_bounds__(256) void k_wt2(const float* __restrict__ W,
                                             unsigned short* __restrict__ wt2) {
  int idx = blockIdx.x * 256 + threadIdx.x;  // < 262144
  int k0 = idx & 31, n = (idx >> 5) & 255, kt = (idx >> 13) & 7, r = idx >> 16;
  float v = W[((size_t)(r * 256) + (kt * 32 + k0)) * 256 + n];
  wt2[idx] = f2bf(v);
}

// ---- weff[q][f][j] = sum_c W[r][f][j*32+c] * att[r][j][c], q = r*2+side ----
__global__ __launch_bounds__(256) void k_weff(const float* __restrict__ W,
                                              const float* __restrict__ asrc,
                                              const float* __restrict__ adst,
                                              float* __restrict__ weff) {
  int idx = blockIdx.x * 256 + threadIdx.x;  // < 16384
  int j = idx & 7, f = (idx >> 3) & 255, q = idx >> 11;
  int r = q >> 1, side = q & 1;
  const float* att = side ? adst : asrc;
  const float* wrow = W + ((size_t)(r * 256) + f) * 256 + j * 32;
  const float* arow = att + (r * 8 + j) * 32;
  float s = 0.f;
#pragma unroll
  for (int c = 0; c < 32; ++c) s += wrow[c] * arow[c];
  weff[idx] = s;
}

// ---- weff -> bf16 k-tiled B layout: weffb[kt][col][k0], col = q*8 + j ------
__global__ __launch_bounds__(256) void k_weffb(const float* __restrict__ weff,
                                               unsigned short* __restrict__ weffb) {
  int idx = blockIdx.x * 256 + threadIdx.x;  // < 16384
  int k0 = idx & 31, col = (idx >> 5) & 63, kt = idx >> 11;
  int q = col >> 3, j = col & 7;
  int f = kt * 32 + k0;
  weffb[idx] = f2bf(weff[(q * 256 + f) * 8 + j]);
}

// ---- CSR build ------------------------------------------------------------
__global__ __launch_bounds__(256) void k_zero(int* __restrict__ p, int n) {
  int i = blockIdx.x * 256 + threadIdx.x;
  if (i < n) p[i] = 0;
}

__global__ __launch_bounds__(256) void k_hist(
    const int* __restrict__ e0, const int* __restrict__ e1,
    const int* __restrict__ e2, const int* __restrict__ e3, int* __restrict__ cnt) {
  int r = blockIdx.y;
  const int* ei = (r == 0) ? e0 : (r == 1) ? e1 : (r == 2) ? e2 : e3;
  int e = blockIdx.x * 256 + threadIdx.x;
  if (e < EE) atomicAdd(&cnt[r * NN + ei[EE + e]], 1);
}

__global__ __launch_bounds__(1024) void k_scan(const int* __restrict__ cnt,
                                               int* __restrict__ rowptr,
                                               int* __restrict__ cursor) {
  int r = blockIdx.x;
  const int* c = cnt + r * NN;
  int* rp = rowptr + r * (NN + 1);
  int* cur = cursor + r * NN;
  __shared__ int part[1024];
  int t = threadIdx.x;
  const int per = 40;  // 1024*40 >= 40000
  int base = t * per;
  int sum = 0;
  for (int i = 0; i < per; ++i) { int idx = base + i; if (idx < NN) sum += c[idx]; }
  part[t] = sum;
  __syncthreads();
  for (int o = 1; o < 1024; o <<= 1) {
    int v = (t >= o) ? part[t - o] : 0;
    __syncthreads();
    part[t] += v;
    __syncthreads();
  }
  int run = part[t] - sum;  // exclusive prefix
  for (int i = 0; i < per; ++i) {
    int idx = base + i;
    if (idx < NN) { rp[idx] = run; cur[idx] = run; run += c[idx]; }
  }
  if (t == 1023) rp[NN] = part[1023];
}

__global__ __launch_bounds__(256) void k_scatter(
    const int* __restrict__ e0, const int* __restrict__ e1,
    const int* __restrict__ e2, const int* __restrict__ e3,
    int* __restrict__ cursor, int* __restrict__ adj) {
  int r = blockIdx.y;
  const int* ei = (r == 0) ? e0 : (r == 1) ? e1 : (r == 2) ? e2 : e3;
  int e = blockIdx.x * 256 + threadIdx.x;
  if (e < EE) {
    int s = ei[e], d = ei[EE + e];
    int pos = atomicAdd(&cursor[r * NN + d], 1);
    adj[(size_t)r * EE + pos] = s;
  }
}

// ---- logits, graph-interleaved: alpf[t][q][n][g][8] = bf16(x) @ weffb -----
__global__ __launch_bounds__(256) void k_algemm(
    const float* __restrict__ x0, const float* __restrict__ x1, const float* __restrict__ x2,
    const float* __restrict__ x3, const float* __restrict__ x4, const float* __restrict__ x5,
    const unsigned short* __restrict__ weffb, float* __restrict__ alpf) {
  __shared__ __attribute__((aligned(16))) unsigned short Alds[64][40];
  __shared__ __attribute__((aligned(16))) unsigned short Blds[64][40];
  int z = blockIdx.y;
  int g = (z >= 3) ? 1 : 0, ty = z - g * 3;
  const float* xp;
  switch (z) { case 0: xp = x0; break; case 1: xp = x1; break; case 2: xp = x2; break;
               case 3: xp = x3; break; case 4: xp = x4; break; default: xp = x5; break; }
  int tid = threadIdx.x;
  int wave = tid >> 6, lane = tid & 63;
  int l15 = lane & 15, l16 = lane >> 4;
  int row0 = blockIdx.x * 64;
  f32x4 acc[4] = {};
  int ar = tid >> 2, ac = (tid & 3) * 8;
  const float* aglob = xp + (size_t)(row0 + ar) * 256 + ac;
  for (int kt = 0; kt < 8; ++kt) {
    f32x4 a0 = *(const f32x4*)(aglob + kt * 32);
    f32x4 a1 = *(const f32x4*)(aglob + kt * 32 + 4);
    *(short8*)(&Alds[ar][ac]) = cvt8(a0, a1);
    short8 bv = *(const short8*)(weffb + kt * 2048 + tid * 8);
    *(short8*)(&Blds[tid >> 2][(tid & 3) * 8]) = bv;
    __syncthreads();
    short8 bf = *(const short8*)(&Blds[wave * 16 + l15][l16 * 8]);
#pragma unroll
    for (int mt = 0; mt < 4; ++mt) {
      short8 af = *(const short8*)(&Alds[mt * 16 + l15][l16 * 8]);
      acc[mt] = __builtin_amdgcn_mfma_f32_16x16x32_bf16(af, bf, acc[mt], 0, 0, 0);
    }
    __syncthreads();
  }
  int col = wave * 16 + l15;
  int q = col >> 3, jj = col & 7;
#pragma unroll
  for (int mt = 0; mt < 4; ++mt)
#pragma unroll
    for (int rr = 0; rr < 4; ++rr) {
      int row = row0 + mt * 16 + l16 * 4 + rr;
      alpf[((size_t)(ty * 8 + q) * NN + row) * 16 + g * 8 + jj] = acc[mt][rr];
    }
}

// ---- per-head global max of alsrc column ----------------------------------
__global__ __launch_bounds__(256) void k_maxsrcp(const float* __restrict__ alpf,
                                                 float* __restrict__ pmax) {
  const int srct[4] = {0, 1, 0, 2};
  int gr = blockIdx.x, slice = blockIdx.y;
  int g = gr >> 2, r = gr & 3;
  const float* col = alpf + ((size_t)(srct[r] * 8 + 2 * r) * NN) * 16 + g * 8;
  int t = threadIdx.x;
  int h = t & 7, chunk = t >> 3;  // 32 chunks
  float m = -1e30f;
  for (int nn = chunk; nn < 1250; nn += 32)
    m = fmaxf(m, col[(size_t)(slice * 1250 + nn) * 16 + h]);
  __shared__ float red[256];
  red[t] = m;
  __syncthreads();
  for (int o = 128; o >= 8; o >>= 1) {
    if (t < o) red[t] = fmaxf(red[t], red[t + o]);
    __syncthreads();
  }
  if (t < 8) pmax[(gr * 32 + slice) * 8 + t] = red[t];
}

__global__ __launch_bounds__(64) void k_maxfin(const float* __restrict__ pmax,
                                               float* __restrict__ maxsrc) {
  int t = threadIdx.x;  // 64 = 8 gr * 8 h
  int gr = t >> 3, h = t & 7;
  float m = -1e30f;
  for (int s = 0; s < 32; ++s) m = fmaxf(m, pmax[(gr * 32 + s) * 8 + h]);
  maxsrc[t] = m;
}

// ---- bf16 MFMA GEMM, BK=64: hbi[r][n][g][256] = bf16(x @ W) ---------------
__global__ __launch_bounds__(256) void k_gemmb8(
    const float* __restrict__ x0, const float* __restrict__ x1, const float* __restrict__ x2,
    const float* __restrict__ x3, const float* __restrict__ x4, const float* __restrict__ x5,
    const unsigned short* __restrict__ wt2, unsigned short* __restrict__ hbi) {
  __shared__ __attribute__((aligned(16))) unsigned short A0lds[64][40];
  __shared__ __attribute__((aligned(16))) unsigned short A1lds[64][40];
  __shared__ __attribute__((aligned(16))) unsigned short B0lds[256][40];
  __shared__ __attribute__((aligned(16))) unsigned short B1lds[256][40];
  const int srct[4] = {0, 1, 0, 2};
  int y = blockIdx.y;  // g*4 + r
  int g = y >> 2, r = y & 3;
  int t6 = g * 3 + srct[r];
  const float* xp;
  switch (t6) { case 0: xp = x0; break; case 1: xp = x1; break; case 2: xp = x2; break;
                case 3: xp = x3; break; case 4: xp = x4; break; default: xp = x5; break; }
  const unsigned short* wtp = wt2 + (size_t)r * (8 * 256 * 32);
  int tid = threadIdx.x;
  int wave = tid >> 6, lane = tid & 63;
  int l15 = lane & 15, l16 = lane >> 4;
  int row0 = blockIdx.x * 64;
  f32x4 acc[4][4] = {};
  int ar = tid >> 2, ac = (tid & 3) * 16;  // 16 floats per thread per kstep
  const float* aglob = xp + (size_t)(row0 + ar) * 256 + ac;
  for (int ks = 0; ks < 4; ++ks) {
    f32x4 a0 = *(const f32x4*)(aglob + ks * 64);
    f32x4 a1 = *(const f32x4*)(aglob + ks * 64 + 4);
    f32x4 a2 = *(const f32x4*)(aglob + ks * 64 + 8);
    f32x4 a3 = *(const f32x4*)(aglob + ks * 64 + 12);
    if (ac < 32) {
      *(short8*)(&A0lds[ar][ac]) = cvt8(a0, a1);
      *(short8*)(&A0lds[ar][ac + 8]) = cvt8(a2, a3);
    } else {
      *(short8*)(&A1lds[ar][ac - 32]) = cvt8(a0, a1);
      *(short8*)(&A1lds[ar][ac - 24]) = cvt8(a2, a3);
    }
    const unsigned short* b0 = wtp + (2 * ks) * 8192;
    const unsigned short* b1 = wtp + (2 * ks + 1) * 8192;
#pragma unroll
    for (int i = 0; i < 4; ++i) {
      int cidx = tid + 256 * i;
      *(short8*)(&B0lds[cidx >> 2][(cidx & 3) * 8]) = *(const short8*)(b0 + cidx * 8);
      *(short8*)(&B1lds[cidx >> 2][(cidx & 3) * 8]) = *(const short8*)(b1 + cidx * 8);
    }
    __syncthreads();
#pragma unroll
    for (int kk = 0; kk < 2; ++kk) {
      short8 af[4], bf[4];
#pragma unroll
      for (int mt = 0; mt < 4; ++mt)
        af[mt] = kk ? *(const short8*)(&A1lds[mt * 16 + l15][l16 * 8])
                    : *(const short8*)(&A0lds[mt * 16 + l15][l16 * 8]);
#pragma unroll
      for (int nt = 0; nt < 4; ++nt)
        bf[nt] = kk ? *(const short8*)(&B1lds[wave * 64 + nt * 16 + l15][l16 * 8])
                    : *(const short8*)(&B0lds[wave * 64 + nt * 16 + l15][l16 * 8]);
#pragma unroll
      for (int mt = 0; mt < 4; ++mt)
#pragma unroll
        for (int nt = 0; nt < 4; ++nt)
          acc[mt][nt] = __builtin_amdgcn_mfma_f32_16x16x32_bf16(af[mt], bf[nt], acc[mt][nt], 0, 0, 0);
    }
    __syncthreads();
  }
#pragma unroll
  for (int mt = 0; mt < 4; ++mt)
#pragma unroll
    for (int nt = 0; nt < 4; ++nt)
#pragma unroll
      for (int rr = 0; rr < 4; ++rr) {
        int row = row0 + mt * 16 + l16 * 4 + rr;
        hbi[((size_t)(r * NN + row) * 2 + g) * 256 + wave * 64 + nt * 16 + l15] =
            f2bf(acc[mt][nt][rr]);
      }
}

// ---- one-relation aggregation for BOTH graphs (interleaved layouts) -------
__device__ __forceinline__ void agg_one2(
    int r, int d, int lane,
    const int* __restrict__ rowptr4, const int* __restrict__ adj4,
    const float* __restrict__ alpf, const unsigned short* __restrict__ hbi,
    const float* __restrict__ maxsrc, f32x4& o0, f32x4& o1) {
  const int srct[4] = {0, 1, 0, 2};
  const int dstt[4] = {1, 0, 2, 0};
  int h = lane >> 3, e8 = lane & 7, ob = lane & 56;
  const int* rowptr = rowptr4 + r * (NN + 1);
  const int* adj = adj4 + (size_t)r * EE;
  const float* asb = alpf + ((size_t)(srct[r] * 8 + 2 * r) * NN) * 16;
  const float* adb = alpf + ((size_t)(dstt[r] * 8 + 2 * r + 1) * NN) * 16;
  const unsigned short* hbr = hbi + (size_t)(r * NN) * 512;

  int beg = rowptr[d], end = rowptr[d + 1];
  float adst0 = adb[(size_t)d * 16 + h];
  float adst1 = adb[(size_t)d * 16 + 8 + h];
  float ub0 = maxsrc[r * 8 + h] + adst0;          // exact segment upper bound
  ub0 = ub0 >= 0.f ? ub0 : 0.2f * ub0;
  float ub1 = maxsrc[(4 + r) * 8 + h] + adst1;
  ub1 = ub1 >= 0.f ? ub1 : 0.2f * ub1;
  float es0 = asb[(size_t)d * 16 + h] + adst0;
  es0 = es0 >= 0.f ? es0 : 0.2f * es0;
  float es1 = asb[(size_t)d * 16 + 8 + h] + adst1;
  es1 = es1 >= 0.f ? es1 : 0.2f * es1;
  float ws0 = __expf(es0 - ub0), ws1 = __expf(es1 - ub1);
  float ssum0 = (e8 == 0) ? ws0 : 0.0f;
  float ssum1 = (e8 == 0) ? ws1 : 0.0f;
  const unsigned short* selfrow = hbr + (size_t)d * 512;
  f32x4 hv0 = ld_bf4(selfrow + lane * 4);
  f32x4 hv1 = ld_bf4(selfrow + 256 + lane * 4);
  f32x4 acc0, acc1;
#pragma unroll
  for (int i = 0; i < 4; ++i) { acc0[i] = ws0 * hv0[i]; acc1[i] = ws1 * hv1[i]; }

  for (int j0 = beg; j0 < end; j0 += 8) {
    int j = j0 + e8;
    bool valid = j < end;
    int s = valid ? adj[j] : d;
    float t0 = asb[(size_t)s * 16 + h] + adst0;
    t0 = t0 >= 0.f ? t0 : 0.2f * t0;
    float t1 = asb[(size_t)s * 16 + 8 + h] + adst1;
    t1 = t1 >= 0.f ? t1 : 0.2f * t1;
    float w0 = valid ? __expf(t0 - ub0) : 0.f;
    float w1 = valid ? __expf(t1 - ub1) : 0.f;
    ssum0 += w0;
    ssum1 += w1;
#pragma unroll
    for (int e2 = 0; e2 < 8; ++e2) {
      int se = __shfl(s, ob + e2, 64);
      float w0e = __shfl(w0, ob + e2, 64);
      float w1e = __shfl(w1, ob + e2, 64);
      const unsigned short* row = hbr + (size_t)se * 512;
      f32x4 g0 = ld_bf4(row + lane * 4);
      f32x4 g1 = ld_bf4(row + 256 + lane * 4);
#pragma unroll
      for (int i = 0; i < 4; ++i) { acc0[i] += w0e * g0[i]; acc1[i] += w1e * g1[i]; }
    }
  }
  ssum0 += __shfl_xor(ssum0, 1, 64);
  ssum0 += __shfl_xor(ssum0, 2, 64);
  ssum0 += __shfl_xor(ssum0, 4, 64);
  ssum1 += __shfl_xor(ssum1, 1, 64);
  ssum1 += __shfl_xor(ssum1, 2, 64);
  ssum1 += __shfl_xor(ssum1, 4, 64);
  float i0 = 1.f / ssum0, i1 = 1.f / ssum1;
#pragma unroll
  for (int i = 0; i < 4; ++i) { o0[i] = acc0[i] * i0; o1[i] = acc1[i] * i1; }
}

// ---- persistent-wave aggregation, both graphs per item --------------------
#define AGG_BLOCKS 1875
__global__ __launch_bounds__(256) void k_agg6(
    const int* __restrict__ rowptr4, const int* __restrict__ adj4,
    const float* __restrict__ alpf, const unsigned short* __restrict__ hbi,
    const float* __restrict__ bias, const float* __restrict__ maxsrc,
    float* __restrict__ out) {
  int lane = threadIdx.x & 63;
  int wgid = (blockIdx.x * 256 + (int)threadIdx.x) >> 6;
  const int NWV = AGG_BLOCKS * 4;
  for (int item = wgid; item < 3 * NN; item += NWV) {
    int y = item / NN;
    int d = item - y * NN;
    f32x4 r0g0, r0g1, r1g0, r1g1;
    int sec;
    if (y == 1) {
      agg_one2(1, d, lane, rowptr4, adj4, alpf, hbi, maxsrc, r0g0, r0g1);
      agg_one2(3, d, lane, rowptr4, adj4, alpf, hbi, maxsrc, r1g0, r1g1);
      f32x4 b1 = *(const f32x4*)(bias + 1 * 256 + lane * 4);
      f32x4 b3 = *(const f32x4*)(bias + 3 * 256 + lane * 4);
#pragma unroll
      for (int i = 0; i < 4; ++i) {
        r0g0[i] = 0.5f * (r0g0[i] + b1[i] + r1g0[i] + b3[i]);
        r0g1[i] = 0.5f * (r0g1[i] + b1[i] + r1g1[i] + b3[i]);
      }
      sec = 0;
    } else {
      int r = (y == 0) ? 0 : 2;
      agg_one2(r, d, lane, rowptr4, adj4, alpf, hbi, maxsrc, r0g0, r0g1);
      f32x4 bv = *(const f32x4*)(bias + r * 256 + lane * 4);
#pragma unroll
      for (int i = 0; i < 4; ++i) { r0g0[i] += bv[i]; r0g1[i] += bv[i]; }
      sec = (y == 0) ? 1 : 2;
    }
    f32x4* op0 = (f32x4*)(out + ((size_t)(0 + sec) * NN + d) * 256 + lane * 4);
    f32x4* op1 = (f32x4*)(out + ((size_t)(3 + sec) * NN + d) * 256 + lane * 4);
    __builtin_nontemporal_store(r0g0, op0);
    __builtin_nontemporal_store(r0g1, op1);
  }
}

extern "C" void kernel_launch(void* const* d_in, const int* in_sizes, int n_in,
                              void* d_out, int out_size, void* d_ws, size_t ws_size,
                              hipStream_t stream) {
  (void)in_sizes; (void)n_in; (void)out_size; (void)ws_size;
  const float* x[6];
  for (int i = 0; i < 6; ++i) x[i] = (const float*)d_in[i];
  const float* W = (const float*)d_in[6];
  const float* att_src = (const float*)d_in[7];
  const float* att_dst = (const float*)d_in[8];
  const float* bias = (const float*)d_in[9];
  const int* ei[4] = {(const int*)d_in[10], (const int*)d_in[11],
                      (const int*)d_in[12], (const int*)d_in[13]};
  float* out = (float*)d_out;

  char* ws = (char*)d_ws;
  size_t off = 0;
  auto take = [&](size_t bytes) -> char* {
    char* p = ws + off;
    off += (bytes + 255) & ~(size_t)255;
    return p;
  };
  unsigned short* hbi = (unsigned short*)take(8ull * NN * 256 * 2);   // 163.8 MB
  float* alpf = (float*)take(3ull * 8 * NN * 16 * 4);                 // 61.4 MB
  unsigned short* wt2 = (unsigned short*)take(4ull * 8 * 256 * 32 * 2);
  float* weff = (float*)take(8ull * 256 * 8 * 4);
  unsigned short* weffb = (unsigned short*)take(8ull * 64 * 32 * 2);
  int* cnt = (int*)take(4ull * NN * 4);
  int* rowptr = (int*)take(4ull * (NN + 1) * 4);
  int* cursor = (int*)take(4ull * NN * 4);
  int* adj = (int*)take(4ull * EE * 4);
  float* pmax = (float*)take(8ull * 32 * 8 * 4);
  float* maxsrc = (float*)take(64ull * 4);

  k_wt2<<<dim3(1024), 256, 0, stream>>>(W, wt2);
  k_weff<<<dim3(64), 256, 0, stream>>>(W, att_src, att_dst, weff);
  k_weffb<<<dim3(64), 256, 0, stream>>>(weff, weffb);
  k_zero<<<dim3(625), 256, 0, stream>>>(cnt, 4 * NN);
  k_hist<<<dim3((EE + 255) / 256, 4), 256, 0, stream>>>(ei[0], ei[1], ei[2], ei[3], cnt);
  k_scan<<<dim3(4), 1024, 0, stream>>>(cnt, rowptr, cursor);
  k_scatter<<<dim3((EE + 255) / 256, 4), 256, 0, stream>>>(ei[0], ei[1], ei[2], ei[3], cursor, adj);
  k_algemm<<<dim3(625, 6), 256, 0, stream>>>(x[0], x[1], x[2], x[3], x[4], x[5],
                                             weffb, alpf);
  k_maxsrcp<<<dim3(8, 32), 256, 0, stream>>>(alpf, pmax);
  k_maxfin<<<dim3(1), 64, 0, stream>>>(pmax, maxsrc);
  k_gemmb8<<<dim3(625, 8), 256, 0, stream>>>(x[0], x[1], x[2], x[3], x[4], x[5],
                                             wt2, hbi);
  k_agg6<<<dim3(AGG_BLOCKS), 256, 0, stream>>>(rowptr, adj, alpf, hbi, bias, maxsrc, out);
}